// Round 17
// baseline (301.637 us; speedup 1.0000x reference)
//
#include <hip/hip_runtime.h>
#include <math.h>

#define NP    520
#define NN    (520*520)
#define HH    512
#define NPIX  (512*512)
#define NB    16
#define NPAIR 8
#define ND    4
#define NF    24
#define KS    544               // padded row stride (elements)
#define RS    576               // padded row count (= 9x64 = 6x96)
#define PLANE ((size_t)RS*KS)
#define S8P   (8*PLANE)         // plane stride within a slab unit [plane2][pair8][PLANE]
#define NBORD2 25424            // extended border cells per image: 18*520 + 502*32
#define PADCH 5536              // pad 16B-chunks per plane: 3*576 + 56*68
#define NBLK2 1057              // (NN+255)/256
#define CSZ   (ND*9*NP)
#define TWO_PI 6.283185307179586f

typedef unsigned short u16;
typedef __attribute__((ext_vector_type(8))) short bf16x8;
typedef __attribute__((ext_vector_type(4))) float f32x4;

__device__ __forceinline__ int wrap520(int t){ t %= NP; return t < 0 ? t + NP : t; }

__device__ __forceinline__ u16 f2bf(float f){
  unsigned u = __float_as_uint(f);
  u += 0x7FFFu + ((u >> 16) & 1u);
  return (u16)(u >> 16);
}
__device__ __forceinline__ float bf2f(u16 h){
  return __uint_as_float(((unsigned)h) << 16);
}
__device__ __forceinline__ void gll16(const u16* g, u16* l){
  __builtin_amdgcn_global_load_lds(
      (const __attribute__((address_space(1))) void*)g,
      (__attribute__((address_space(3))) void*)l, 16, 0, 0);
}
template<int N> __device__ __forceinline__ void vmwait(){
  if constexpr (N == 0)       asm volatile("s_waitcnt vmcnt(0)" ::: "memory");
  else if constexpr (N == 4)  asm volatile("s_waitcnt vmcnt(4)" ::: "memory");
  else if constexpr (N == 6)  asm volatile("s_waitcnt vmcnt(6)" ::: "memory");
  else if constexpr (N == 8)  asm volatile("s_waitcnt vmcnt(8)" ::: "memory");
  else if constexpr (N == 12) asm volatile("s_waitcnt vmcnt(12)" ::: "memory");
}
#define MF(a,b,c) __builtin_amdgcn_mfma_f32_16x16x32_bf16((a),(b),(c),0,0,0)

// ================= mega setup kernel =================
// segments (linear grid): [0,nA) zero MA pads | [+PLANE) W slabs | [+18) taper |
// [+9*NP) T table (inline twiddles) | [+ND*81) R (inline weight normalization)
__global__ __launch_bounds__(256) void setup_k(const float* __restrict__ bk,
                                               const float* __restrict__ cw,
                                               const float* __restrict__ scale,
                                               u16* __restrict__ slabs,
                                               u16* __restrict__ wf, u16* __restrict__ wi,
                                               float* __restrict__ r_row, float* __restrict__ r_col,
                                               float* __restrict__ T, float* __restrict__ R){
  int idx = blockIdx.x*256 + threadIdx.x;
  const int nA = 16*PADCH;
  if (idx < nA){
    int pl = idx / PADCH, cc = idx % PADCH;
    int row, col;
    if (cc < 1728){ row = cc/3; col = 520 + (cc%3)*8; }
    else { int c2 = cc - 1728; row = 520 + c2/68; col = (c2%68)*8; }
    bf16x8 z = {0,0,0,0,0,0,0,0};
    *(bf16x8*)(slabs + (size_t)pl*PLANE + (size_t)row*KS + col) = z;
    return;
  }
  idx -= nA;
  if (idx < (int)PLANE){
    int r = idx / KS, k = idx % KS;
    float fr=0.f, fi=0.f, ir=0.f, ii=0.f;
    if (r < NP && k < NP){
      int m = (int)(((long long)r * (long long)k) % NP);
      float ang = TWO_PI * (float)m / (float)NP;
      float s, c; sincosf(ang, &s, &c);
      fr = c; fi = -s;
      ir = c * (1.0f/NP); ii = s * (1.0f/NP);
    }
    wf[0*PLANE+idx] = f2bf(fr); wf[1*PLANE+idx] = f2bf(fi);
    wi[0*PLANE+idx] = f2bf(ir); wi[1*PLANE+idx] = f2bf(ii);
    return;
  }
  idx -= (int)PLANE;
  if (idx < 18){
    int k = idx % 9;
    bool rowp = (idx < 9);
    float proj[9];
    for (int m = 0; m < 9; ++m){
      float a = 0.f;
      for (int j = 0; j < 9; ++j) a += rowp ? bk[m*9+j] : bk[j*9+m];
      proj[m] = a;
    }
    float acc = 0.f;
    for (int m = 0; m + k < 9; ++m) acc += proj[m] * proj[m+k];
    (rowp ? r_row : r_col)[k] = acc;
    return;
  }
  idx -= 18;
  if (idx < 9*NP){
    int i = idx / NP, v = idx % NP;
    float tr = 0.f, ti = 0.f;
    #pragma unroll
    for (int j = 0; j < 9; ++j){
      int m = wrap520(v*(j-4));
      float ang = TWO_PI * (float)m / (float)NP;
      float s, c; sincosf(ang, &s, &c);
      float w = bk[i*9+j];
      tr += w * c; ti += w * (-s);
    }
    T[idx] = tr; T[9*NP + idx] = ti;
    return;
  }
  idx -= 9*NP;
  if (idx >= ND*81) return;
  // R with inline weight normalization
  int d = idx / 81, t = idx % 81;
  int di = t/9 - 4, dj = t%9 - 4;
  int i0 = di > 0 ? di : 0, i1 = di < 0 ? 4+di : 4;
  int j0 = dj > 0 ? dj : 0, j1 = dj < 0 ? 4+dj : 4;
  float acc = 0.f;
  for (int f = 0; f < NF; ++f){
    const float* wp = cw + (d*NF+f)*25;
    float mean = 0.f;
    for (int k = 0; k < 25; ++k) mean += wp[k];
    mean *= (1.0f/25.0f);
    float ss = 0.f;
    for (int k = 0; k < 25; ++k){ float dv = wp[k]-mean; ss += dv*dv; }
    float sc = scale[d*NF+f] / sqrtf(ss);
    float part = 0.f;
    for (int i = i0; i <= i1; ++i)
      for (int j = j0; j <= j1; ++j)
        part += (wp[i*5+j]-mean) * (wp[(i-di)*5 + (j-dj)]-mean);
    acc += sc*sc*part;
  }
  R[idx] = acc;
}

// C table with inline twiddles: C[d][t][v] = sum_s R[d][t][s] * e_v[s-4]
__global__ void C_k(const float* __restrict__ R, float* __restrict__ Ctab){
  int idx = blockIdx.x*blockDim.x + threadIdx.x;
  if (idx >= ND*9*NP) return;
  int v = idx % NP, t9 = idx / NP;
  int d = t9 / 9, t = t9 % 9;
  float cr = 0.f, ci = 0.f;
  #pragma unroll
  for (int s = 0; s < 9; ++s){
    int m = wrap520(v*(s-4));
    float ang = TWO_PI * (float)m / (float)NP;
    float sn, cs; sincosf(ang, &sn, &cs);
    float r = R[d*81 + t*9 + s];
    cr += r * cs;
    ci += r * (-sn);
  }
  Ctab[idx] = cr; Ctab[CSZ + idx] = ci;
}

// wiener masks (bf16 out): inline otf + inline e9 twiddles; Tb/Ctab slices via LDS;
// one f32x4 reduction tree; per-block pcv partials (no atomics)
__global__ __launch_bounds__(256) void denomMT2_k(
    const float* __restrict__ Tb, const float* __restrict__ Ctab,
    const float* __restrict__ alpha,
    u16* __restrict__ MTre, u16* __restrict__ MTim, float* __restrict__ pcv){
  __shared__ float tbs[2][2][9];     // [v-slot][re/im][i]
  __shared__ float cts[2][2][36];    // [v-slot][re/im][d*9+t]
  __shared__ f32x4 red[256];
  const int tid = threadIdx.x;
  const int p0 = blockIdx.x*256;
  const int p = p0 + tid;
  const int v0 = p0 / NP;
  {
    if (tid < 36){
      int s = tid / 18, rem = tid % 18, h = rem / 9, i = rem % 9;
      int vv = v0 + s; if (vv >= NP) vv = NP-1;
      tbs[s][h][i] = Tb[h*(9*NP) + i*NP + vv];
    } else if (tid < 36 + 144){
      int t = tid - 36;
      int s = t / 72, rem = t % 72, h = rem / 36, j = rem % 36;
      int vv = v0 + s; if (vv >= NP) vv = NP-1;
      cts[s][h][j] = Ctab[(size_t)h*CSZ + (size_t)j*NP + vv];
    }
  }
  __syncthreads();
  f32x4 contrib = {0.f, 0.f, 0.f, 0.f};
  if (p < NN){
    int u = p % NP;
    int sl = p/NP - v0;
    float er9[9], ei9[9];
    #pragma unroll
    for (int i = 0; i < 9; ++i){
      int m = wrap520(u*(i-4));
      float ang = TWO_PI * (float)m / (float)NP;
      float sn, cs; sincosf(ang, &sn, &cs);
      er9[i] = cs; ei9[i] = -sn;
    }
    float ar = 0.f, ai = 0.f;
    #pragma unroll
    for (int i = 0; i < 9; ++i){
      float tr = tbs[sl][0][i], ti = tbs[sl][1][i];
      ar += er9[i]*tr - ei9[i]*ti;
      ai += er9[i]*ti + ei9[i]*tr;
    }
    float B2 = ar*ar + ai*ai;
    #pragma unroll
    for (int d = 0; d < ND; ++d){
      float S = 0.f;
      #pragma unroll
      for (int t = 0; t < 9; ++t)
        S += er9[t]*cts[sl][0][d*9+t] - ei9[t]*cts[sl][1][d*9+t];
      float dv = B2 + expf(alpha[d]) * S;
      MTre[(size_t)d*NN + p] = f2bf(ar / dv);
      MTim[(size_t)d*NN + p] = f2bf(-ai / dv);
      contrib[d] = B2 / (dv*dv);
    }
  }
  red[tid] = contrib; __syncthreads();
  for (int s = 128; s > 0; s >>= 1){
    if (tid < s) red[tid] += red[tid+s];
    __syncthreads();
  }
  if (tid < ND) pcv[(size_t)blockIdx.x*ND + tid] = red[0][tid];
}

// finisher: sum per-block partials (deterministic) + write cstdn outputs
__global__ __launch_bounds__(256) void cstdn2_k(const float* __restrict__ stdn,
                                                const float* __restrict__ pcv,
                                                float* __restrict__ out){
  __shared__ float red[256];
  int t = threadIdx.x;
  int d = t & 3, ch = t >> 2;
  float acc = 0.f;
  for (int b = ch; b < NBLK2; b += 64) acc += pcv[(size_t)b*ND + d];
  red[t] = acc; __syncthreads();
  for (int s = 128; s >= 4; s >>= 1){
    if (t < s) red[t] += red[t+s];
    __syncthreads();
  }
  if (t < NB*ND){
    int b = t >> 2, d2 = t & 3;
    float s = stdn[b];
    out[(size_t)NB*ND*NPIX + t] = sqrtf(s*s*red[d2]*(1.0f/(float)NN));
  }
}

// ========== fused pad-transpose (interior chunks) + extended border (rest) ==========
// pad role: blocks [0, 9*9*NB). writes slab rows 9..510, col chunks 16..503 only.
// border role: remaining blocks. cells: {slab row in 18 border rows, all cols} U
// {slab rows 9..510, cols in 0..15 & 504..519}. taper/blur where in true border.
__global__ __launch_bounds__(256) void pb_k(const float* __restrict__ x,
                                            const float* __restrict__ bk,
                                            const float* __restrict__ r_row,
                                            const float* __restrict__ r_col,
                                            u16* __restrict__ MA){
  const int PBLK = 9*9*NB;
  if ((int)blockIdx.x < PBLK){
    __shared__ float tile[64][65];
    const int b  = blockIdx.x;
    const int q  = b / 81;
    const int by = (b / 9) % 9;
    const int bx = b % 9;
    const int r0 = by * 64;
    const int c0 = bx * 64;
    const int t  = threadIdx.x;
    const float* xq = x + (size_t)q*NPIX;
    const int jl = t & 63, ib = t >> 6;
    const bool fast = (c0 >= 64 && c0 <= 448 && r0 >= 64 && r0 <= 448);

    if (fast){
      #pragma unroll 1
      for (int pass = 0; pass < 16; ++pass){
        int il = ib + pass*4;
        tile[il][jl] = xq[(size_t)(c0+il-4)*HH + (r0+jl-4)];
      }
    } else {
      #pragma unroll 1
      for (int pass = 0; pass < 16; ++pass){
        int il = ib + pass*4;
        int I = c0 + il, J = r0 + jl;
        float v = 0.f;
        if (I < NP && J < NP){
          int si = I - 4; si = (si < 0) ? (-si-1) : ((si >= HH) ? (2*HH-1-si) : si);
          int sj = J - 4; sj = (sj < 0) ? (-sj-1) : ((sj >= HH) ? (2*HH-1-sj) : sj);
          v = xq[(size_t)si*HH + sj];
        }
        tile[il][jl] = v;
      }
    }
    __syncthreads();

    const int cchunk = t & 7, rb = t >> 3;
    const int pair = q >> 1, pl = q & 1;
    #pragma unroll
    for (int half = 0; half < 2; ++half){
      int rl = rb + half*32;
      int r = r0 + rl, cg = c0 + cchunk*8;
      if (r < 9 || r >= 511 || cg < 16 || cg >= 504) continue;
      bf16x8 vh;
      #pragma unroll
      for (int e = 0; e < 8; ++e)
        vh[e] = (short)f2bf(tile[cchunk*8+e][rl]);
      size_t o = (size_t)pair*PLANE + (size_t)r*KS + cg;
      *(bf16x8*)(MA + (size_t)pl*S8P + o) = vh;
    }
    return;
  }

  // border role
  __shared__ float bks[81], rr_[9], rc_[9];
  if (threadIdx.x < 81) bks[threadIdx.x] = bk[threadIdx.x];
  if (threadIdx.x < 9){ rr_[threadIdx.x] = r_row[threadIdx.x]; rc_[threadIdx.x] = r_col[threadIdx.x]; }
  __syncthreads();
  int idx = ((int)blockIdx.x - PBLK)*256 + threadIdx.x;
  if (idx >= NB*NBORD2) return;
  int q = idx / NBORD2, t = idx % NBORD2;
  // I = image row (slab col), J = image col (slab row)
  int I, J;
  if (t < 9360){            // slab-row border: J in 18 values, I free
    int ji = t / 520;
    J = (ji < 9) ? ji : 502 + ji;
    I = t % 520;
  } else {                  // extended slab-col border: I in 32 values, J 9..510
    int s = t - 9360;
    int iI = s / 502;
    J = 9 + s % 502;
    I = (iI < 16) ? iI : 488 + iI;
  }
  const float* xq = x + (size_t)q*NPIX;
  auto XP = [&](int ii, int jj)->float{
    int si = ii - 4; si = (si < 0) ? (-si-1) : ((si >= HH) ? (2*HH-1-si) : si);
    int sj = jj - 4; sj = (sj < 0) ? (-sj-1) : ((sj >= HH) ? (2*HH-1-sj) : sj);
    return xq[(size_t)si*HH + sj];
  };
  float v = XP(I, J);
  if (I < 9 || I >= 511 || J < 9 || J >= 511){
    float brv = (I < 9) ? rr_[I] : ((I >= 511) ? rr_[519-I] : 0.f);
    float bcv = (J < 9) ? rc_[J] : ((J >= 511) ? rc_[519-J] : 0.f);
    brv /= rr_[0]; bcv /= rc_[0];
    float tp = (1.f - brv) * (1.f - bcv);
    float blur = 0.f;
    for (int a = 0; a < 9; ++a){
      int ii = wrap520(I - a + 4);
      for (int b2 = 0; b2 < 9; ++b2){
        int jj = wrap520(J - b2 + 4);
        blur += bks[a*9+b2] * XP(ii, jj);
      }
    }
    v = tp*v + (1.f - tp)*blur;
  }
  int pair = q >> 1, pl = q & 1;
  MA[(size_t)pl*S8P + (size_t)pair*PLANE + (size_t)J*KS + I] = f2bf(v);
}

// ========== maskF (fallback path only), bf16 masks ==========
__global__ __launch_bounds__(256) void maskF_k(const u16* __restrict__ IN, u16* __restrict__ OUT,
                                               const u16* __restrict__ Mre, const u16* __restrict__ Mim){
  int idx = blockIdx.x*256 + threadIdx.x;
  if (idx >= NPAIR*NP*65) return;
  int pr = idx / (NP*65), rem = idx % (NP*65);
  int r = rem / 65, c0 = (rem % 65)*8;
  size_t o = (size_t)pr*PLANE + (size_t)r*KS + c0;
  bf16x8 qr = *(const bf16x8*)(IN + 0*S8P + o);
  bf16x8 qi = *(const bf16x8*)(IN + 1*S8P + o);
  const u16* mrp = Mre + (size_t)r*NP + c0;
  const u16* mip = Mim + (size_t)r*NP + c0;
  bf16x8 o0, o1;
  #pragma unroll
  for (int e = 0; e < 8; ++e){
    float vr = bf2f((u16)qr[e]), vi = bf2f((u16)qi[e]);
    float mr = bf2f(mrp[e]), mi = bf2f(mip[e]);
    o0[e] = (short)f2bf(vr*mr - vi*mi);
    o1[e] = (short)f2bf(vr*mi + vi*mr);
  }
  *(bf16x8*)(OUT + 0*S8P + o) = o0;
  *(bf16x8*)(OUT + 1*S8P + o) = o1;
}

// ===== MFMA complex GEMM: BMxBM tile, BK=32, 3-buffer depth-2 prefetch,     =====
// ===== counted vmcnt, phase-split MFMA, scalar epilogue (round-16 form)     =====
template<int BM, int CROP, int MASKOUT>
__global__ __launch_bounds__(256) void gemm_k(
    const u16* __restrict__ P, size_t pPl, size_t pZp, size_t pZd,
    const u16* __restrict__ Q, size_t qPl, size_t qZp, size_t qZd,
    u16* __restrict__ O, size_t oPl, size_t oZp, size_t oZd,
    float* __restrict__ cropOut, int dBase,
    const u16* __restrict__ Mre, const u16* __restrict__ Mim)
{
  constexpr int NW = 4;
  constexpr int FR = BM/32;
  constexpr int TR = BM/16;
  constexpr int LPW = 4*TR/NW;
  constexpr int PLSTR = BM*32;
  constexpr int BUF = 4*PLSTR;
  constexpr int NK = KS/32;
  __shared__ u16 lds[3*BUF];
  const int tid = threadIdx.x;
  const int l = tid & 63, w = tid >> 6;

  // bijective XCD chunk swizzle
  const int gx = gridDim.x, gy = gridDim.y;
  int lin = blockIdx.x + gx*(blockIdx.y + gy*blockIdx.z);
  int ntot = gx*gy*gridDim.z;
  int q8 = ntot >> 3, r8 = ntot & 7;
  int xcd = lin & 7, id8 = lin >> 3;
  int nl = (xcd < r8 ? xcd*(q8+1) : r8*(q8+1) + (xcd-r8)*q8) + id8;
  int BX = nl % gx; int t2 = nl / gx;
  int BY = t2 % gy; int BZ = t2 / gy;

  const int pair = BZ & 7;
  const int dd = dBase + (BZ >> 3);
  const int R0 = BY * BM, C0 = BX * BM;

  const u16* Pb = P + (size_t)pair*pZp + (size_t)dd*pZd;
  const u16* Qb = Q + (size_t)pair*qZp + (size_t)dd*qZd;

  const int s = l >> 2;
  const int cs8 = ((l & 3) ^ ((s >> 1) & 3)) * 8;
  const size_t pOff0 = (size_t)(R0 + s)*KS + cs8;
  const size_t qOff0 = (size_t)(C0 + s)*KS + cs8;

  const int lm = l & 15, lc = l >> 4;
  const int wm = w >> 1, wn = w & 1;

  f32x4 zero4 = {0.f, 0.f, 0.f, 0.f};
  f32x4 aRe[FR][FR], aIm[FR][FR];
  #pragma unroll
  for (int i = 0; i < FR; ++i)
    #pragma unroll
    for (int j = 0; j < FR; ++j){ aRe[i][j] = zero4; aIm[i][j] = zero4; }

  auto STAGE = [&](int bi, int k0){
    u16* dst = lds + bi*BUF;
    #pragma unroll
    for (int i = 0; i < LPW; ++i){
      int t = w + i*NW;
      int q2 = t / TR, r2 = t % TR;
      const u16* src = (q2 < 2) ? (Pb + (size_t)q2*pPl + pOff0)
                                : (Qb + (size_t)(q2-2)*qPl + qOff0);
      gll16(src + (size_t)(r2*16)*KS + k0, dst + q2*PLSTR + r2*512);
    }
  };

  STAGE(0, 0);
  STAGE(1, 32);

  #pragma unroll 1
  for (int kt = 0; kt < NK; ++kt){
    if (kt + 1 < NK) vmwait<LPW>(); else vmwait<0>();
    __builtin_amdgcn_sched_barrier(0);
    __builtin_amdgcn_s_barrier();            // tile kt landed (all waves)
    __builtin_amdgcn_sched_barrier(0);

    const u16* buf = lds + (kt%3)*BUF;
    bf16x8 pf[FR][2];
    #pragma unroll
    for (int mi = 0; mi < FR; ++mi){
      int r = wm*(FR*16) + mi*16 + lm;
      int co = ((lc ^ ((r >> 1) & 3)) << 3);
      pf[mi][0] = *(const bf16x8*)(buf + 0*PLSTR + r*32 + co);
      pf[mi][1] = *(const bf16x8*)(buf + 1*PLSTR + r*32 + co);
    }
    #pragma unroll
    for (int ni = 0; ni < FR; ++ni){
      int rq = wn*(FR*16) + ni*16 + lm;
      int cq = ((lc ^ ((rq >> 1) & 3)) << 3);
      bf16x8 q0 = *(const bf16x8*)(buf + 2*PLSTR + rq*32 + cq);
      bf16x8 q1 = *(const bf16x8*)(buf + 3*PLSTR + rq*32 + cq);
      if (ni == 0){
        if (kt + 2 < NK) STAGE((kt+2)%3, (kt+2)*32);
      } else {
        __builtin_amdgcn_sched_barrier(0);
        __builtin_amdgcn_s_barrier();        // phase boundary (reads issued above)
      }
      asm volatile("s_waitcnt lgkmcnt(0)" ::: "memory");
      __builtin_amdgcn_sched_barrier(0);
      __builtin_amdgcn_s_setprio(1);
      #pragma unroll
      for (int mi = 0; mi < FR; ++mi){
        bf16x8 nw = pf[mi][1] ^ (short)0x8000;   // -P.im
        f32x4 re = aRe[mi][ni], im = aIm[mi][ni];
        re = MF(pf[mi][0], q0, re);
        re = MF(nw,        q1, re);
        im = MF(pf[mi][0], q1, im);
        im = MF(pf[mi][1], q0, im);
        aRe[mi][ni] = re; aIm[mi][ni] = im;
      }
      __builtin_amdgcn_s_setprio(0);
    }
  }

  // epilogue (scalar)
  u16* Ob = O ? (O + (size_t)pair*oZp + (size_t)dd*oZd) : nullptr;
  #pragma unroll
  for (int mi = 0; mi < FR; ++mi)
    #pragma unroll
    for (int ni = 0; ni < FR; ++ni){
      int cb = C0 + wn*(FR*16) + ni*16 + lm;
      int rb = R0 + wm*(FR*16) + mi*16 + lc*4;
      #pragma unroll
      for (int e = 0; e < 4; ++e){
        int rr = rb + e;
        float vr = aRe[mi][ni][e], vi = aIm[mi][ni][e];
        if (CROP){
          if (rr >= 4 && rr < 516 && cb >= 4 && cb < 516){
            size_t px = (size_t)(rr-4)*HH + (cb-4);
            cropOut[((size_t)(2*pair  )*ND + dd)*NPIX + px] = vr;
            cropOut[((size_t)(2*pair+1)*ND + dd)*NPIX + px] = vi;
          }
        } else if (MASKOUT){
          if (cb < KS){
            size_t o = (size_t)rr*KS + cb;
            size_t mo = (size_t)(rr < NP ? rr : 0)*NP + (cb < NP ? cb : 0);  // clamp; vr=vi=0 there
            #pragma unroll
            for (int d2 = 0; d2 < ND; ++d2){
              float mr = bf2f(Mre[(size_t)d2*NN + mo]);
              float mi2 = bf2f(Mim[(size_t)d2*NN + mo]);
              u16* Od = O + (size_t)d2*oZd + (size_t)pair*oZp;
              Od[0*oPl+o] = f2bf(vr*mr - vi*mi2);
              Od[1*oPl+o] = f2bf(vr*mi2 + vi*mr);
            }
          }
        } else {
          if (cb < KS){
            size_t o = (size_t)rr*KS + cb;
            Ob[0*oPl+o] = f2bf(vr);
            Ob[1*oPl+o] = f2bf(vi);
          }
        }
      }
    }
}

// ================= host =================

extern "C" void kernel_launch(void* const* d_in, const int* in_sizes, int n_in,
                              void* d_out, int out_size, void* d_ws, size_t ws_size,
                              hipStream_t stream){
  const float* x     = (const float*)d_in[0];
  const float* bk    = (const float*)d_in[1];
  const float* stdn  = (const float*)d_in[2];
  const float* cw    = (const float*)d_in[3];
  const float* scale = (const float*)d_in[4];
  const float* alpha = (const float*)d_in[5];
  float* out = (float*)d_out;

  char* base = (char*)d_ws;
  const size_t UNIT = 16*PLANE*sizeof(u16);   // one slab unit [plane2][pair8][PLANE]
  size_t off;
  auto alloc = [&](size_t bytes)->void*{
    void* p = base + off;
    off += (bytes + 255) & ~(size_t)255;
    return p;
  };

  u16 *MA, *MB, *MC, *Dm, *Do, *WF, *WI, *MTre, *MTim;
  float *Tb, *Rarr, *Ctab, *r_row, *r_col, *pcv;
  auto layout = [&](bool bigL){
    off = 0;
    MA = (u16*)alloc(UNIT);
    MB = (u16*)alloc(UNIT);
    if (bigL){ Dm = (u16*)alloc(4*UNIT); Do = (u16*)alloc(4*UNIT); MC = nullptr; }
    else     { MC = (u16*)alloc(UNIT);   Dm = nullptr; Do = nullptr; }
    WF = (u16*)alloc(2*PLANE*sizeof(u16));
    WI = (u16*)alloc(2*PLANE*sizeof(u16));
    MTre = (u16*)alloc((size_t)ND*NN*2);
    MTim = (u16*)alloc((size_t)ND*NN*2);
    Tb   = (float*)alloc(2*9*NP*4);
    Rarr = (float*)alloc(ND*81*4);
    Ctab = (float*)alloc(2*CSZ*4);
    r_row = (float*)alloc(64);
    r_col = (float*)alloc(64);
    pcv  = (float*)alloc((size_t)NBLK2*ND*4);
    return off;
  };
  bool big = (layout(true) <= ws_size);
  if (!big){
    if (layout(false) > ws_size) return;  // insufficient workspace
  }

  {
    int ztot = 16*PADCH + (int)PLANE + 18 + 9*NP + ND*81;
    setup_k<<<(ztot+255)/256, 256, 0, stream>>>(bk, cw, scale, MA, WF, WI,
                                                r_row, r_col, Tb, Rarr);
  }
  C_k     <<<(ND*9*NP+255)/256, 256, 0, stream>>>(Rarr, Ctab);
  denomMT2_k<<<NBLK2, 256, 0, stream>>>(Tb, Ctab, alpha, MTre, MTim, pcv);
  cstdn2_k<<<1, 256, 0, stream>>>(stdn, pcv, out);
  {
    int pbBlocks = 9*9*NB + (NB*NBORD2 + 255)/256;
    pb_k<<<pbBlocks, 256, 0, stream>>>(x, bk, r_row, r_col, MA);
  }

  // G5: C5 = Wf * xp2   (BM=64, 9x9x8 = 648 blocks)  -> MB
  gemm_k<64,0,0><<<dim3(9,9,8),256,0,stream>>>(
      WF, PLANE, 0, 0,   MA, S8P, PLANE, 0,   MB, S8P, PLANE, 0,
      nullptr, 0, nullptr, nullptr);

  if (big){
    // G6+mask: Dm_d = (Wf * C5) .* MT_d for all 4 d (fused epilogue)
    gemm_k<64,0,1><<<dim3(9,9,8),256,0,stream>>>(
        WF, PLANE, 0, 0,   MB, S8P, PLANE, 0,   Dm, S8P, PLANE, 16*PLANE,
        nullptr, 0, MTre, MTim);
    // G7: Do_d = Wi * Dm_d  (BM=96, 6x6x32 = 1152 blocks)
    gemm_k<96,0,0><<<dim3(6,6,32),256,0,stream>>>(
        WI, PLANE, 0, 0,   Dm, S8P, PLANE, 16*PLANE,   Do, S8P, PLANE, 16*PLANE,
        nullptr, 0, nullptr, nullptr);
    // G8: out_d = Do_d * Wi (crop)
    gemm_k<96,1,0><<<dim3(6,6,32),256,0,stream>>>(
        Do, S8P, PLANE, 16*PLANE,   WI, PLANE, 0, 0,   nullptr, 0, 0, 0,
        out, 0, nullptr, nullptr);
  } else {
    // fallback: sequential d, per-d mask pass
    gemm_k<64,0,0><<<dim3(9,9,8),256,0,stream>>>(
        WF, PLANE, 0, 0,   MB, S8P, PLANE, 0,   MC, S8P, PLANE, 0,
        nullptr, 0, nullptr, nullptr);
    const int mgrid = (NPAIR*NP*65 + 255)/256;
    for (int d = 0; d < ND; ++d){
      maskF_k<<<mgrid,256,0,stream>>>(MC, MA, MTre + (size_t)d*NN, MTim + (size_t)d*NN);
      gemm_k<96,0,0><<<dim3(6,6,8),256,0,stream>>>(
          WI, PLANE, 0, 0,   MA, S8P, PLANE, 0,   MB, S8P, PLANE, 0,
          nullptr, 0, nullptr, nullptr);
      gemm_k<96,1,0><<<dim3(6,6,8),256,0,stream>>>(
          MB, S8P, PLANE, 0,   WI, PLANE, 0, 0,   nullptr, 0, 0, 0,
          out, d, nullptr, nullptr);
    }
  }
}

// Round 18
// 269.145 us; speedup vs baseline: 1.1207x; 1.1207x over previous
//
#include <hip/hip_runtime.h>
#include <math.h>

#define NP    520
#define NN    (520*520)
#define HH    512
#define NPIX  (512*512)
#define NB    16
#define NPAIR 8
#define ND    4
#define NF    24
#define KS    544               // padded row stride (elements)
#define RS    576               // padded row count (= 9x64 = 6x96)
#define PLANE ((size_t)RS*KS)
#define S8P   (8*PLANE)         // plane stride within a slab unit [plane2][pair8][PLANE]
#define E9SZ  (NP*9)
#define CSZ   (ND*9*NP)
#define NBORD 18396
#define PADCH 5536              // pad 16B-chunks per plane: 3*576 + 56*68
#define NBLK2 1057              // (NN+255)/256
#define TWO_PI 6.283185307179586f

typedef unsigned short u16;
typedef __attribute__((ext_vector_type(8))) short bf16x8;
typedef __attribute__((ext_vector_type(4))) float f32x4;

__device__ __forceinline__ int wrap520(int t){ t %= NP; return t < 0 ? t + NP : t; }

__device__ __forceinline__ u16 f2bf(float f){
  unsigned u = __float_as_uint(f);
  u += 0x7FFFu + ((u >> 16) & 1u);
  return (u16)(u >> 16);
}
__device__ __forceinline__ float bf2f(u16 h){
  return __uint_as_float(((unsigned)h) << 16);
}
__device__ __forceinline__ void gll16(const u16* g, u16* l){
  __builtin_amdgcn_global_load_lds(
      (const __attribute__((address_space(1))) void*)g,
      (__attribute__((address_space(3))) void*)l, 16, 0, 0);
}
template<int N> __device__ __forceinline__ void vmwait(){
  if constexpr (N == 0)       asm volatile("s_waitcnt vmcnt(0)" ::: "memory");
  else if constexpr (N == 4)  asm volatile("s_waitcnt vmcnt(4)" ::: "memory");
  else if constexpr (N == 6)  asm volatile("s_waitcnt vmcnt(6)" ::: "memory");
  else if constexpr (N == 8)  asm volatile("s_waitcnt vmcnt(8)" ::: "memory");
  else if constexpr (N == 12) asm volatile("s_waitcnt vmcnt(12)" ::: "memory");
}
#define MF(a,b,c) __builtin_amdgcn_mfma_f32_16x16x32_bf16((a),(b),(c),0,0,0)

// ================= fused setup kernels =================

// zero pad cells of MA's 16 slices + build W slabs (2 planes each, bf16)
__global__ __launch_bounds__(256) void zwb_k(u16* __restrict__ slabs,
                                             u16* __restrict__ wf, u16* __restrict__ wi){
  int idx = blockIdx.x*256 + threadIdx.x;
  const int nA = 16*PADCH;
  if (idx < nA){
    int pl = idx / PADCH, cc = idx % PADCH;
    int row, col;
    if (cc < 1728){ row = cc/3; col = 520 + (cc%3)*8; }
    else { int c2 = cc - 1728; row = 520 + c2/68; col = (c2%68)*8; }
    bf16x8 z = {0,0,0,0,0,0,0,0};
    *(bf16x8*)(slabs + (size_t)pl*PLANE + (size_t)row*KS + col) = z;
    return;
  }
  idx -= nA;
  if (idx >= (int)PLANE) return;
  int r = idx / KS, k = idx % KS;
  float fr=0.f, fi=0.f, ir=0.f, ii=0.f;
  if (r < NP && k < NP){
    int m = (int)(((long long)r * (long long)k) % NP);
    float ang = TWO_PI * (float)m / (float)NP;
    float s, c; sincosf(ang, &s, &c);
    fr = c; fi = -s;
    ir = c * (1.0f/NP); ii = s * (1.0f/NP);
  }
  wf[0*PLANE+idx] = f2bf(fr); wf[1*PLANE+idx] = f2bf(fi);
  wi[0*PLANE+idx] = f2bf(ir); wi[1*PLANE+idx] = f2bf(ii);
}

// setup1: e9 twiddles + taper autocorr + weight normalization
__global__ __launch_bounds__(256) void setup1_k(const float* __restrict__ bk,
                                                const float* __restrict__ cw,
                                                const float* __restrict__ scale,
                                                float* __restrict__ e9,
                                                float* __restrict__ r_row, float* __restrict__ r_col,
                                                float* __restrict__ wn){
  int idx = blockIdx.x*256 + threadIdx.x;
  if (idx < NP*9){
    int u = idx / 9, t = idx % 9;
    int m = wrap520(u*(t-4));
    float ang = TWO_PI * (float)m / (float)NP;
    float s, c; sincosf(ang, &s, &c);
    e9[idx] = c; e9[E9SZ + idx] = -s;
    return;
  }
  idx -= NP*9;
  if (idx < 18){
    int k = idx % 9;
    bool rowp = (idx < 9);
    float proj[9];
    for (int m = 0; m < 9; ++m){
      float a = 0.f;
      for (int j = 0; j < 9; ++j) a += rowp ? bk[m*9+j] : bk[j*9+m];
      proj[m] = a;
    }
    float acc = 0.f;
    for (int m = 0; m + k < 9; ++m) acc += proj[m] * proj[m+k];
    (rowp ? r_row : r_col)[k] = acc;
    return;
  }
  idx -= 18;
  if (idx >= ND*NF) return;
  const float* wp = cw + idx*25;
  float mean = 0.f;
  for (int k = 0; k < 25; ++k) mean += wp[k];
  mean *= (1.0f/25.0f);
  float ss = 0.f;
  for (int k = 0; k < 25; ++k){ float d = wp[k]-mean; ss += d*d; }
  float sc = scale[idx] / sqrtf(ss);
  for (int k = 0; k < 25; ++k) wn[idx*25+k] = (wp[k]-mean)*sc;
}

// setup2: blur row-table T + filter autocorrelation R
__global__ __launch_bounds__(256) void setup2_k(const float* __restrict__ bk,
                                                const float* __restrict__ e9,
                                                const float* __restrict__ wn,
                                                float* __restrict__ T, float* __restrict__ R){
  int idx = blockIdx.x*256 + threadIdx.x;
  if (idx < 9*NP){
    int i = idx / NP, v = idx % NP;
    float tr = 0.f, ti = 0.f;
    #pragma unroll
    for (int j = 0; j < 9; ++j){
      float w = bk[i*9+j];
      tr += w * e9[v*9+j];
      ti += w * e9[E9SZ + v*9+j];
    }
    T[idx] = tr; T[9*NP + idx] = ti;
    return;
  }
  idx -= 9*NP;
  if (idx >= ND*81) return;
  int d = idx / 81, t = idx % 81;
  int di = t/9 - 4, dj = t%9 - 4;
  int i0 = di > 0 ? di : 0, i1 = di < 0 ? 4+di : 4;
  int j0 = dj > 0 ? dj : 0, j1 = dj < 0 ? 4+dj : 4;
  float acc = 0.f;
  for (int f = 0; f < NF; ++f){
    const float* w = wn + (d*NF+f)*25;
    for (int i = i0; i <= i1; ++i)
      for (int j = j0; j <= j1; ++j)
        acc += w[i*5+j] * w[(i-di)*5 + (j-dj)];
  }
  R[idx] = acc;
}

__global__ void C_k(const float* __restrict__ R, const float* __restrict__ e9,
                    float* __restrict__ Ctab){
  int idx = blockIdx.x*blockDim.x + threadIdx.x;
  if (idx >= ND*9*NP) return;
  int v = idx % NP, t9 = idx / NP;
  int d = t9 / 9, t = t9 % 9;
  float cr = 0.f, ci = 0.f;
  #pragma unroll
  for (int s = 0; s < 9; ++s){
    float r = R[d*81 + t*9 + s];
    cr += r * e9[v*9+s];
    ci += r * e9[E9SZ + v*9+s];
  }
  Ctab[idx] = cr; Ctab[CSZ + idx] = ci;
}

// wiener masks (bf16 out): inline otf, all 4 d per thread; Tb/Ctab staged in LDS
// (block spans at most 2 distinct v values); one f32x4 reduction tree; pcv partials
__global__ __launch_bounds__(256) void denomMT2_k(
    const float* __restrict__ Tb, const float* __restrict__ e9,
    const float* __restrict__ Ctab, const float* __restrict__ alpha,
    u16* __restrict__ MTre, u16* __restrict__ MTim, float* __restrict__ pcv){
  __shared__ float e9r[2304], e9i[2304];
  __shared__ float tbs[2][2][9];     // [v-slot][re/im][i]
  __shared__ float cts[2][2][36];    // [v-slot][re/im][d*9+t]
  __shared__ f32x4 red[256];
  const int tid = threadIdx.x;
  const int p0 = blockIdx.x*256;
  const int p = p0 + tid;
  const int v0 = p0 / NP;
  {
    int u0 = p0 % NP;
    for (int i = tid; i < 2304; i += 256){
      int row = i / 9, col = i % 9;
      int uu = u0 + row; if (uu >= NP) uu -= NP;
      e9r[i] = e9[uu*9 + col];
      e9i[i] = e9[E9SZ + uu*9 + col];
    }
    if (tid < 36){
      int s = tid / 18, rem = tid % 18, h = rem / 9, i = rem % 9;
      int vv = v0 + s; if (vv >= NP) vv = NP-1;
      tbs[s][h][i] = Tb[h*(9*NP) + i*NP + vv];
    } else if (tid < 36 + 144){
      int t = tid - 36;
      int s = t / 72, rem = t % 72, h = rem / 36, j = rem % 36;
      int vv = v0 + s; if (vv >= NP) vv = NP-1;
      cts[s][h][j] = Ctab[(size_t)h*CSZ + (size_t)j*NP + vv];
    }
  }
  __syncthreads();
  f32x4 contrib = {0.f, 0.f, 0.f, 0.f};
  if (p < NN){
    int sl = p/NP - v0;
    float er9[9], ei9[9];
    #pragma unroll
    for (int i = 0; i < 9; ++i){ er9[i] = e9r[tid*9+i]; ei9[i] = e9i[tid*9+i]; }
    float ar = 0.f, ai = 0.f;
    #pragma unroll
    for (int i = 0; i < 9; ++i){
      float tr = tbs[sl][0][i], ti = tbs[sl][1][i];
      ar += er9[i]*tr - ei9[i]*ti;
      ai += er9[i]*ti + ei9[i]*tr;
    }
    float B2 = ar*ar + ai*ai;
    #pragma unroll
    for (int d = 0; d < ND; ++d){
      float S = 0.f;
      #pragma unroll
      for (int t = 0; t < 9; ++t)
        S += er9[t]*cts[sl][0][d*9+t] - ei9[t]*cts[sl][1][d*9+t];
      float dv = B2 + expf(alpha[d]) * S;
      MTre[(size_t)d*NN + p] = f2bf(ar / dv);
      MTim[(size_t)d*NN + p] = f2bf(-ai / dv);
      contrib[d] = B2 / (dv*dv);
    }
  }
  red[tid] = contrib; __syncthreads();
  for (int s = 128; s > 0; s >>= 1){
    if (tid < s) red[tid] += red[tid+s];
    __syncthreads();
  }
  if (tid < ND) pcv[(size_t)blockIdx.x*ND + tid] = red[0][tid];
}

// finisher: sum per-block partials (deterministic) + write cstdn outputs
__global__ __launch_bounds__(256) void cstdn2_k(const float* __restrict__ stdn,
                                                const float* __restrict__ pcv,
                                                float* __restrict__ out){
  __shared__ float red[256];
  int t = threadIdx.x;
  int d = t & 3, ch = t >> 2;
  float acc = 0.f;
  for (int b = ch; b < NBLK2; b += 64) acc += pcv[(size_t)b*ND + d];
  red[t] = acc; __syncthreads();
  for (int s = 128; s >= 4; s >>= 1){
    if (t < s) red[t] += red[t+s];
    __syncthreads();
  }
  if (t < NB*ND){
    int b = t >> 2, d2 = t & 3;
    float s = stdn[b];
    out[(size_t)NB*ND*NPIX + t] = sqrtf(s*s*red[d2]*(1.0f/(float)NN));
  }
}

// ========== pad + transpose only ==========
__global__ __launch_bounds__(256) void pad_tr_k(const float* __restrict__ x,
                                                u16* __restrict__ MA){
  __shared__ float tile[64][65];
  const int q  = blockIdx.z;
  const int r0 = blockIdx.y * 64;
  const int c0 = blockIdx.x * 64;
  const int t  = threadIdx.x;
  const float* xq = x + (size_t)q*NPIX;
  const int jl = t & 63, ib = t >> 6;
  const bool fast = (c0 >= 64 && c0 <= 448 && r0 >= 64 && r0 <= 448);

  if (fast){
    #pragma unroll 1
    for (int pass = 0; pass < 16; ++pass){
      int il = ib + pass*4;
      tile[il][jl] = xq[(size_t)(c0+il-4)*HH + (r0+jl-4)];
    }
  } else {
    #pragma unroll 1
    for (int pass = 0; pass < 16; ++pass){
      int il = ib + pass*4;
      int I = c0 + il, J = r0 + jl;
      float v = 0.f;
      if (I < NP && J < NP){
        int si = I - 4; si = (si < 0) ? (-si-1) : ((si >= HH) ? (2*HH-1-si) : si);
        int sj = J - 4; sj = (sj < 0) ? (-sj-1) : ((sj >= HH) ? (2*HH-1-sj) : sj);
        v = xq[(size_t)si*HH + sj];
      }
      tile[il][jl] = v;
    }
  }
  __syncthreads();

  const int cchunk = t & 7, rb = t >> 3;
  const int pair = q >> 1, pl = q & 1;
  #pragma unroll
  for (int half = 0; half < 2; ++half){
    int rl = rb + half*32;
    int r = r0 + rl, cg = c0 + cchunk*8;
    if (r >= NP || cg >= NP) continue;
    bf16x8 vh;
    #pragma unroll
    for (int e = 0; e < 8; ++e)
      vh[e] = (short)f2bf(tile[cchunk*8+e][rl]);
    size_t o = (size_t)pair*PLANE + (size_t)r*KS + cg;
    *(bf16x8*)(MA + (size_t)pl*S8P + o) = vh;
  }
}

// ========== border taper+blur ==========
__global__ __launch_bounds__(256) void border_k(const float* __restrict__ x,
                                                const float* __restrict__ bk,
                                                const float* __restrict__ r_row,
                                                const float* __restrict__ r_col,
                                                u16* __restrict__ MA){
  __shared__ float bks[81], rr_[9], rc_[9];
  if (threadIdx.x < 81) bks[threadIdx.x] = bk[threadIdx.x];
  if (threadIdx.x < 9){ rr_[threadIdx.x] = r_row[threadIdx.x]; rc_[threadIdx.x] = r_col[threadIdx.x]; }
  __syncthreads();
  int idx = blockIdx.x*256 + threadIdx.x;
  if (idx >= NB*NBORD) return;
  int q = idx / NBORD, t = idx % NBORD;
  int I, J;
  if (t < 9360){ int ri = t / 520; I = (ri < 9) ? ri : 502 + ri; J = t % 520; }
  else { int s = t - 9360; I = 9 + s / 18; int ci = s % 18; J = (ci < 9) ? ci : 502 + ci; }
  const float* xq = x + (size_t)q*NPIX;
  auto XP = [&](int ii, int jj)->float{
    int si = ii - 4; si = (si < 0) ? (-si-1) : ((si >= HH) ? (2*HH-1-si) : si);
    int sj = jj - 4; sj = (sj < 0) ? (-sj-1) : ((sj >= HH) ? (2*HH-1-sj) : sj);
    return xq[(size_t)si*HH + sj];
  };
  float v = XP(I, J);
  float brv = (I < 9) ? rr_[I] : ((I >= 511) ? rr_[519-I] : 0.f);
  float bcv = (J < 9) ? rc_[J] : ((J >= 511) ? rc_[519-J] : 0.f);
  brv /= rr_[0]; bcv /= rc_[0];
  float tp = (1.f - brv) * (1.f - bcv);
  float blur = 0.f;
  for (int a = 0; a < 9; ++a){
    int ii = wrap520(I - a + 4);
    for (int b2 = 0; b2 < 9; ++b2){
      int jj = wrap520(J - b2 + 4);
      blur += bks[a*9+b2] * XP(ii, jj);
    }
  }
  v = tp*v + (1.f - tp)*blur;
  int pair = q >> 1, pl = q & 1;
  MA[(size_t)pl*S8P + (size_t)pair*PLANE + (size_t)J*KS + I] = f2bf(v);
}

// ========== maskF (fallback path only), bf16 masks ==========
__global__ __launch_bounds__(256) void maskF_k(const u16* __restrict__ IN, u16* __restrict__ OUT,
                                               const u16* __restrict__ Mre, const u16* __restrict__ Mim){
  int idx = blockIdx.x*256 + threadIdx.x;
  if (idx >= NPAIR*NP*65) return;
  int pr = idx / (NP*65), rem = idx % (NP*65);
  int r = rem / 65, c0 = (rem % 65)*8;
  size_t o = (size_t)pr*PLANE + (size_t)r*KS + c0;
  bf16x8 qr = *(const bf16x8*)(IN + 0*S8P + o);
  bf16x8 qi = *(const bf16x8*)(IN + 1*S8P + o);
  const u16* mrp = Mre + (size_t)r*NP + c0;
  const u16* mip = Mim + (size_t)r*NP + c0;
  bf16x8 o0, o1;
  #pragma unroll
  for (int e = 0; e < 8; ++e){
    float vr = bf2f((u16)qr[e]), vi = bf2f((u16)qi[e]);
    float mr = bf2f(mrp[e]), mi = bf2f(mip[e]);
    o0[e] = (short)f2bf(vr*mr - vi*mi);
    o1[e] = (short)f2bf(vr*mi + vi*mr);
  }
  *(bf16x8*)(OUT + 0*S8P + o) = o0;
  *(bf16x8*)(OUT + 1*S8P + o) = o1;
}

// ===== MFMA complex GEMM: BMxBM tile, BK=32, 3-buffer depth-2 prefetch,     =====
// ===== counted vmcnt, phase-split MFMA, SCALAR epilogue (round-14 form)     =====
template<int BM, int CROP, int MASKOUT>
__global__ __launch_bounds__(256) void gemm_k(
    const u16* __restrict__ P, size_t pPl, size_t pZp, size_t pZd,
    const u16* __restrict__ Q, size_t qPl, size_t qZp, size_t qZd,
    u16* __restrict__ O, size_t oPl, size_t oZp, size_t oZd,
    float* __restrict__ cropOut, int dBase,
    const u16* __restrict__ Mre, const u16* __restrict__ Mim)
{
  constexpr int NW = 4;
  constexpr int FR = BM/32;
  constexpr int TR = BM/16;
  constexpr int LPW = 4*TR/NW;
  constexpr int PLSTR = BM*32;
  constexpr int BUF = 4*PLSTR;
  constexpr int NK = KS/32;
  __shared__ u16 lds[3*BUF];
  const int tid = threadIdx.x;
  const int l = tid & 63, w = tid >> 6;

  // bijective XCD chunk swizzle
  const int gx = gridDim.x, gy = gridDim.y;
  int lin = blockIdx.x + gx*(blockIdx.y + gy*blockIdx.z);
  int ntot = gx*gy*gridDim.z;
  int q8 = ntot >> 3, r8 = ntot & 7;
  int xcd = lin & 7, id8 = lin >> 3;
  int nl = (xcd < r8 ? xcd*(q8+1) : r8*(q8+1) + (xcd-r8)*q8) + id8;
  int BX = nl % gx; int t2 = nl / gx;
  int BY = t2 % gy; int BZ = t2 / gy;

  const int pair = BZ & 7;
  const int dd = dBase + (BZ >> 3);
  const int R0 = BY * BM, C0 = BX * BM;

  const u16* Pb = P + (size_t)pair*pZp + (size_t)dd*pZd;
  const u16* Qb = Q + (size_t)pair*qZp + (size_t)dd*qZd;

  const int s = l >> 2;
  const int cs8 = ((l & 3) ^ ((s >> 1) & 3)) * 8;
  const size_t pOff0 = (size_t)(R0 + s)*KS + cs8;
  const size_t qOff0 = (size_t)(C0 + s)*KS + cs8;

  const int lm = l & 15, lc = l >> 4;
  const int wm = w >> 1, wn = w & 1;

  f32x4 zero4 = {0.f, 0.f, 0.f, 0.f};
  f32x4 aRe[FR][FR], aIm[FR][FR];
  #pragma unroll
  for (int i = 0; i < FR; ++i)
    #pragma unroll
    for (int j = 0; j < FR; ++j){ aRe[i][j] = zero4; aIm[i][j] = zero4; }

  auto STAGE = [&](int bi, int k0){
    u16* dst = lds + bi*BUF;
    #pragma unroll
    for (int i = 0; i < LPW; ++i){
      int t = w + i*NW;
      int q2 = t / TR, r2 = t % TR;
      const u16* src = (q2 < 2) ? (Pb + (size_t)q2*pPl + pOff0)
                                : (Qb + (size_t)(q2-2)*qPl + qOff0);
      gll16(src + (size_t)(r2*16)*KS + k0, dst + q2*PLSTR + r2*512);
    }
  };

  STAGE(0, 0);
  STAGE(1, 32);

  #pragma unroll 1
  for (int kt = 0; kt < NK; ++kt){
    if (kt + 1 < NK) vmwait<LPW>(); else vmwait<0>();
    __builtin_amdgcn_sched_barrier(0);
    __builtin_amdgcn_s_barrier();            // tile kt landed (all waves)
    __builtin_amdgcn_sched_barrier(0);

    const u16* buf = lds + (kt%3)*BUF;
    bf16x8 pf[FR][2];
    #pragma unroll
    for (int mi = 0; mi < FR; ++mi){
      int r = wm*(FR*16) + mi*16 + lm;
      int co = ((lc ^ ((r >> 1) & 3)) << 3);
      pf[mi][0] = *(const bf16x8*)(buf + 0*PLSTR + r*32 + co);
      pf[mi][1] = *(const bf16x8*)(buf + 1*PLSTR + r*32 + co);
    }
    #pragma unroll
    for (int ni = 0; ni < FR; ++ni){
      int rq = wn*(FR*16) + ni*16 + lm;
      int cq = ((lc ^ ((rq >> 1) & 3)) << 3);
      bf16x8 q0 = *(const bf16x8*)(buf + 2*PLSTR + rq*32 + cq);
      bf16x8 q1 = *(const bf16x8*)(buf + 3*PLSTR + rq*32 + cq);
      if (ni == 0){
        if (kt + 2 < NK) STAGE((kt+2)%3, (kt+2)*32);
      } else {
        __builtin_amdgcn_sched_barrier(0);
        __builtin_amdgcn_s_barrier();        // phase boundary (reads issued above)
      }
      asm volatile("s_waitcnt lgkmcnt(0)" ::: "memory");
      __builtin_amdgcn_sched_barrier(0);
      __builtin_amdgcn_s_setprio(1);
      #pragma unroll
      for (int mi = 0; mi < FR; ++mi){
        bf16x8 nw = pf[mi][1] ^ (short)0x8000;   // -P.im
        f32x4 re = aRe[mi][ni], im = aIm[mi][ni];
        re = MF(pf[mi][0], q0, re);
        re = MF(nw,        q1, re);
        im = MF(pf[mi][0], q1, im);
        im = MF(pf[mi][1], q0, im);
        aRe[mi][ni] = re; aIm[mi][ni] = im;
      }
      __builtin_amdgcn_s_setprio(0);
    }
  }

  // epilogue (scalar, round-14 form)
  u16* Ob = O ? (O + (size_t)pair*oZp + (size_t)dd*oZd) : nullptr;
  #pragma unroll
  for (int mi = 0; mi < FR; ++mi)
    #pragma unroll
    for (int ni = 0; ni < FR; ++ni){
      int cb = C0 + wn*(FR*16) + ni*16 + lm;
      int rb = R0 + wm*(FR*16) + mi*16 + lc*4;
      #pragma unroll
      for (int e = 0; e < 4; ++e){
        int rr = rb + e;
        float vr = aRe[mi][ni][e], vi = aIm[mi][ni][e];
        if (CROP){
          if (rr >= 4 && rr < 516 && cb >= 4 && cb < 516){
            size_t px = (size_t)(rr-4)*HH + (cb-4);
            cropOut[((size_t)(2*pair  )*ND + dd)*NPIX + px] = vr;
            cropOut[((size_t)(2*pair+1)*ND + dd)*NPIX + px] = vi;
          }
        } else if (MASKOUT){
          if (cb < KS){
            size_t o = (size_t)rr*KS + cb;
            size_t mo = (size_t)(rr < NP ? rr : 0)*NP + (cb < NP ? cb : 0);  // clamp; vr=vi=0 there
            #pragma unroll
            for (int d2 = 0; d2 < ND; ++d2){
              float mr = bf2f(Mre[(size_t)d2*NN + mo]);
              float mi2 = bf2f(Mim[(size_t)d2*NN + mo]);
              u16* Od = O + (size_t)d2*oZd + (size_t)pair*oZp;
              Od[0*oPl+o] = f2bf(vr*mr - vi*mi2);
              Od[1*oPl+o] = f2bf(vr*mi2 + vi*mr);
            }
          }
        } else {
          if (cb < KS){
            size_t o = (size_t)rr*KS + cb;
            Ob[0*oPl+o] = f2bf(vr);
            Ob[1*oPl+o] = f2bf(vi);
          }
        }
      }
    }
}

// ================= host =================

extern "C" void kernel_launch(void* const* d_in, const int* in_sizes, int n_in,
                              void* d_out, int out_size, void* d_ws, size_t ws_size,
                              hipStream_t stream){
  const float* x     = (const float*)d_in[0];
  const float* bk    = (const float*)d_in[1];
  const float* stdn  = (const float*)d_in[2];
  const float* cw    = (const float*)d_in[3];
  const float* scale = (const float*)d_in[4];
  const float* alpha = (const float*)d_in[5];
  float* out = (float*)d_out;

  char* base = (char*)d_ws;
  const size_t UNIT = 16*PLANE*sizeof(u16);   // one slab unit [plane2][pair8][PLANE]
  size_t off;
  auto alloc = [&](size_t bytes)->void*{
    void* p = base + off;
    off += (bytes + 255) & ~(size_t)255;
    return p;
  };

  u16 *MA, *MB, *MC, *Dm, *Do, *WF, *WI, *MTre, *MTim;
  float *e9, *Tb, *Rarr, *Ctab, *r_row, *r_col, *wn, *pcv;
  auto layout = [&](bool bigL){
    off = 0;
    MA = (u16*)alloc(UNIT);
    MB = (u16*)alloc(UNIT);
    if (bigL){ Dm = (u16*)alloc(4*UNIT); Do = (u16*)alloc(4*UNIT); MC = nullptr; }
    else     { MC = (u16*)alloc(UNIT);   Dm = nullptr; Do = nullptr; }
    WF = (u16*)alloc(2*PLANE*sizeof(u16));
    WI = (u16*)alloc(2*PLANE*sizeof(u16));
    MTre = (u16*)alloc((size_t)ND*NN*2);
    MTim = (u16*)alloc((size_t)ND*NN*2);
    e9   = (float*)alloc(2*E9SZ*4);
    Tb   = (float*)alloc(2*9*NP*4);
    Rarr = (float*)alloc(ND*81*4);
    Ctab = (float*)alloc(2*CSZ*4);
    r_row = (float*)alloc(64);
    r_col = (float*)alloc(64);
    wn   = (float*)alloc(ND*NF*25*4);
    pcv  = (float*)alloc((size_t)NBLK2*ND*4);
    return off;
  };
  bool big = (layout(true) <= ws_size);
  if (!big){
    if (layout(false) > ws_size) return;  // insufficient workspace
  }

  {
    int ztot = 16*PADCH + (int)PLANE;
    zwb_k<<<(ztot+255)/256, 256, 0, stream>>>(MA, WF, WI);
  }
  setup1_k<<<(NP*9+18+ND*NF+255)/256, 256, 0, stream>>>(bk, cw, scale, e9, r_row, r_col, wn);
  setup2_k<<<(9*NP+ND*81+255)/256, 256, 0, stream>>>(bk, e9, wn, Tb, Rarr);
  C_k     <<<(ND*9*NP+255)/256, 256, 0, stream>>>(Rarr, e9, Ctab);
  denomMT2_k<<<NBLK2, 256, 0, stream>>>(Tb, e9, Ctab, alpha, MTre, MTim, pcv);
  cstdn2_k<<<1, 256, 0, stream>>>(stdn, pcv, out);
  pad_tr_k<<<dim3(9, 9, NB), 256, 0, stream>>>(x, MA);
  border_k<<<(NB*NBORD+255)/256, 256, 0, stream>>>(x, bk, r_row, r_col, MA);

  // G5: C5 = Wf * xp2   (BM=64, 9x9x8 = 648 blocks)  -> MB
  gemm_k<64,0,0><<<dim3(9,9,8),256,0,stream>>>(
      WF, PLANE, 0, 0,   MA, S8P, PLANE, 0,   MB, S8P, PLANE, 0,
      nullptr, 0, nullptr, nullptr);

  if (big){
    // G6+mask: Dm_d = (Wf * C5) .* MT_d for all 4 d (fused epilogue)
    gemm_k<64,0,1><<<dim3(9,9,8),256,0,stream>>>(
        WF, PLANE, 0, 0,   MB, S8P, PLANE, 0,   Dm, S8P, PLANE, 16*PLANE,
        nullptr, 0, MTre, MTim);
    // G7: Do_d = Wi * Dm_d  (BM=96, 6x6x32 = 1152 blocks)
    gemm_k<96,0,0><<<dim3(6,6,32),256,0,stream>>>(
        WI, PLANE, 0, 0,   Dm, S8P, PLANE, 16*PLANE,   Do, S8P, PLANE, 16*PLANE,
        nullptr, 0, nullptr, nullptr);
    // G8: out_d = Do_d * Wi (crop)
    gemm_k<96,1,0><<<dim3(6,6,32),256,0,stream>>>(
        Do, S8P, PLANE, 16*PLANE,   WI, PLANE, 0, 0,   nullptr, 0, 0, 0,
        out, 0, nullptr, nullptr);
  } else {
    // fallback: sequential d, per-d mask pass
    gemm_k<64,0,0><<<dim3(9,9,8),256,0,stream>>>(
        WF, PLANE, 0, 0,   MB, S8P, PLANE, 0,   MC, S8P, PLANE, 0,
        nullptr, 0, nullptr, nullptr);
    const int mgrid = (NPAIR*NP*65 + 255)/256;
    for (int d = 0; d < ND; ++d){
      maskF_k<<<mgrid,256,0,stream>>>(MC, MA, MTre + (size_t)d*NN, MTim + (size_t)d*NN);
      gemm_k<96,0,0><<<dim3(6,6,8),256,0,stream>>>(
          WI, PLANE, 0, 0,   MA, S8P, PLANE, 0,   MB, S8P, PLANE, 0,
          nullptr, 0, nullptr, nullptr);
      gemm_k<96,1,0><<<dim3(6,6,8),256,0,stream>>>(
          MB, S8P, PLANE, 0,   WI, PLANE, 0, 0,   nullptr, 0, 0, 0,
          out, d, nullptr, nullptr);
    }
  }
}